// Round 8
// baseline (29.796 us; speedup 1.0000x reference)
//
#include <hip/hip_runtime.h>
#include <hip/hip_bf16.h>

namespace {

// may_alias: LDS is written as u64 (bf16x4 packs) and read as bf16x8.
typedef short bf16x8 __attribute__((ext_vector_type(8), may_alias));
typedef unsigned long long u64_ma __attribute__((may_alias));
typedef __attribute__((ext_vector_type(16))) float f32x16;   // MFMA 32x32 acc

constexpr int kB = 32, kT = 16384, kCin = 32, kCout = 32;
constexpr int kL = 128;            // owned rows per chunk
constexpr int kK = 32;             // zero-state warm-up
constexpr int kChunks = kT / kL;   // 128
constexpr int kWpB = 4;            // waves per block
constexpr int kRS = 80;            // LDS bf16 row stride: 64B data + 16B pad
                                   // (bank start = 20*row mod 32, period 8 ->
                                   //  uniform 4-way b128 floor, no swizzle)
constexpr int kStageRows = 34;     // 32 rows + 2 halo rows
constexpr int kStageB = kStageRows * kRS;  // 2720 B per wave

__device__ __forceinline__ unsigned bfbits(float f) {
  return (unsigned)__builtin_bit_cast(unsigned short, __float2bfloat16(f));
}

// Wave = one (b, chunk). u staged coalesced f32 -> cvt -> bf16 LDS (80B rows)
// -> 6x ds_read_b128 A-fragments -> 6x mfma_32x32x16_bf16 -> shfl_xor half
// exchange (R5-proven semantics) -> redundant register IIR chain.
__global__ __launch_bounds__(256, 4) void mimo_mfma5(
    const float* __restrict__ u,        // [B, T, CIN]
    const float* __restrict__ x0,       // [B, 2, COUT]
    const float* __restrict__ a_coeff,  // [2, COUT]
    const float* __restrict__ b_coeff,  // [3, CIN, COUT]
    float* __restrict__ out)            // [B, T, COUT]
{
  __shared__ char lds[kWpB][kStageB];   // 10.6 KiB per block

  const int tidx = (int)threadIdx.x;
  const int lane = tidx & 63;
  const int col  = lane & 31;          // output channel / time-row within tile
  const int g    = lane >> 5;          // lane-half (k-slot group / C-row +4)
  const int widx = tidx >> 6;
  const int wid  = (int)blockIdx.x * kWpB + widx;
  const int b     = wid >> 7;          // 0..31
  const int chunk = wid & (kChunks - 1);
  const int t0     = chunk * kL;
  const int tstart = chunk ? (t0 - kK) : 0;
  const int ntiles = (t0 + kL - tstart) >> 5;   // 4 (chunk 0) or 5

  char* Lw = &lds[widx][0];

  // B fragments: slot (g,j) of K-step (tau,h) = b_coeff[2-tau][16g+8h+j][col].
  // A uses the SAME slot->channel map, so the HW k-order cancels.
  bf16x8 Bf[3][2];
#pragma unroll
  for (int tau = 0; tau < 3; ++tau)
#pragma unroll
    for (int h = 0; h < 2; ++h) {
      const float* bp = b_coeff + (size_t)(2 - tau) * kCin * kCout
                        + (16 * g + 8 * h) * kCout + col;
      bf16x8 fr;
#pragma unroll
      for (int j = 0; j < 8; ++j)
        fr[j] = (short)__builtin_bit_cast(unsigned short, __float2bfloat16(bp[j * kCout]));
      Bf[tau][h] = fr;
    }

  const float a1 = a_coeff[col];
  const float a2 = a_coeff[kCout + col];
  float s1 = 0.f, s2 = 0.f;
  if (chunk == 0) {
    s1 = x0[(b * 2 + 1) * kCout + col];
    s2 = x0[(b * 2 + 0) * kCout + col];
  }

  const float* ub = u + (size_t)b * kT * kCin;
  float* ob = out + (size_t)b * kT * kCout;

  // Coalesced stage load: f4-index f of a 34-row stage starting at rowbase.
  auto gload = [&](int rowbase, int f) -> float4 {
    const int grow = rowbase + (f >> 3);
    if (grow >= 0)
      return *(const float4*)(ub + (size_t)grow * kCin + ((f & 7) << 2));
    float4 z; z.x = 0.f; z.y = 0.f; z.z = 0.f; z.w = 0.f;
    return z;
  };
  // cvt f32x4 -> bf16x4 and ds_write_b64 into the 80B-stride stage.
  auto stash = [&](int f, float4 v) {
    const unsigned lo = bfbits(v.x) | (bfbits(v.y) << 16);
    const unsigned hi = bfbits(v.z) | (bfbits(v.w) << 16);
    const unsigned long long q = ((unsigned long long)hi << 32) | lo;
    *(u64_ma*)(Lw + (f >> 3) * kRS + (f & 7) * 8) = q;
  };

  // -------- prologue: stage rows [tstart-2, tstart+32) --------
  {
    const int rowbase = tstart - 2;   // rows < 0 (chunk 0) staged as zeros
    float4 p0 = gload(rowbase, lane);
    float4 p1 = gload(rowbase, lane + 64);
    float4 p2 = gload(rowbase, lane + 128);
    float4 p3 = gload(rowbase, lane + 192);
    float4 p4;
    if (lane < 16) p4 = gload(rowbase, lane + 256);
    stash(lane, p0);
    stash(lane + 64, p1);
    stash(lane + 128, p2);
    stash(lane + 192, p3);
    if (lane < 16) stash(lane + 256, p4);
  }
  asm volatile("" ::: "memory");   // stage writes ordered before tile-0 reads

  for (int tile = 0; tile < ntiles; ++tile) {
    const int tbase = tstart + 32 * tile;
    const bool last = (tile + 1 == ntiles);

    // T14 issue-early: next stage's coalesced global loads fly during compute.
    float4 n0, n1, n2, n3, n4;
    if (!last) {
      const int rowbase = tbase + 30;   // (tbase+32) - 2
      n0 = gload(rowbase, lane);
      n1 = gload(rowbase, lane + 64);
      n2 = gload(rowbase, lane + 128);
      n3 = gload(rowbase, lane + 192);
      if (lane < 16) n4 = gload(rowbase, lane + 256);
    }

    // ---- FIR: 6x ds_read_b128 (bf16 direct) + 6 MFMAs ----
    f32x16 acc;
#pragma unroll
    for (int i = 0; i < 16; ++i) acc[i] = 0.f;
#pragma unroll
    for (int tau = 0; tau < 3; ++tau) {
      const char* rp = Lw + (col + tau) * kRS + 32 * g;
#pragma unroll
      for (int h = 0; h < 2; ++h) {
        const bf16x8 fa = *(const bf16x8*)(rp + 16 * h);
        acc = __builtin_amdgcn_mfma_f32_32x32x16_bf16(fa, Bf[tau][h], acc, 0, 0, 0);
      }
    }

    // ---- full-acc half exchange: 16 INDEPENDENT shuffles (R5-proven) ----
    float oth[16];
#pragma unroll
    for (int i = 0; i < 16; ++i) oth[i] = __shfl_xor(acc[i], 32);

    // ---- IIR: both halves run the identical 32-step chain redundantly ----
    // C/D layout: reg r (half gg) holds row (r&3) + 8*(r>>2) + 4*gg.
    const bool owned = (tbase >= t0);
    float x1 = s1, x2 = s2;
#pragma unroll
    for (int j = 0; j < 32; ++j) {
      const int reg = 4 * (j >> 3) + (j & 3);
      const int g4  = (j >> 2) & 1;
      const float v = (g4 == g) ? acc[reg] : oth[reg];
      const float xn = fmaf(a1, x1, fmaf(a2, x2, v));
      if (owned && g4 == g) ob[(size_t)(tbase + j) * kCout + col] = xn;
      x2 = x1; x1 = xn;
    }
    s1 = x1; s2 = x2;

    // write-late: refill the single stage buffer. Barriers pin instruction
    // order; the wave-local LDS FIFO executes DS ops in issue order.
    if (!last) {
      asm volatile("" ::: "memory");   // this tile's ds_reads issue first
      stash(lane, n0);
      stash(lane + 64, n1);
      stash(lane + 128, n2);
      stash(lane + 192, n3);
      if (lane < 16) stash(lane + 256, n4);
      asm volatile("" ::: "memory");   // refill before next tile's ds_reads
    }
  }
}

}  // namespace

extern "C" void kernel_launch(void* const* d_in, const int* in_sizes, int n_in,
                              void* d_out, int out_size, void* d_ws, size_t ws_size,
                              hipStream_t stream) {
  const float* u  = (const float*)d_in[0];
  const float* x0 = (const float*)d_in[1];
  const float* a  = (const float*)d_in[2];
  const float* bb = (const float*)d_in[3];
  float* out = (float*)d_out;

  dim3 grid(kB * kChunks / kWpB);  // 4096 waves / 4 = 1024 blocks
  dim3 block(256);
  hipLaunchKernelGGL(mimo_mfma5, grid, block, 0, stream, u, x0, a, bb, out);
}